// Round 3
// baseline (859.605 us; speedup 1.0000x reference)
//
#include <hip/hip_runtime.h>
#include <hip/hip_bf16.h>

#define V 3
#define N 4096
#define D 512
#define H 128
#define C 5

// ---------------- K1: h = data@gac_w, mlp = data@mlp_w ----------------
#define TN1 16
__global__ __launch_bounds__(128) void k1_gemm(
    const float* __restrict__ data,
    const float* __restrict__ gac_w,
    const float* __restrict__ mlp_w,
    float* __restrict__ h_out, float* __restrict__ mlp_out)
{
  const int v = blockIdx.y;
  const int n0 = blockIdx.x * TN1;
  const int t = threadIdx.x;
  __shared__ float ds[D][20];   // transposed data tile; row stride 80B (16B-aligned float4)
  const float* dp = data + ((size_t)v*N + n0)*D;
  for (int j = t; j < TN1*D; j += 128){
    int r = j >> 9, d = j & (D-1);
    ds[d][r] = dp[(size_t)r*D + d];
  }
  __syncthreads();
  float ag[TN1], am[TN1];
  #pragma unroll
  for (int r=0;r<TN1;r++){ ag[r]=0.f; am[r]=0.f; }
  const float* gw = gac_w + (size_t)v*D*H + t;
  const float* mw = mlp_w + (size_t)v*D*H + t;
  for (int d=0; d<D; d++){
    float wg = gw[(size_t)d*H];
    float wm = mw[(size_t)d*H];
    const float4* p = (const float4*)&ds[d][0];
    float4 x0=p[0], x1=p[1], x2=p[2], x3=p[3];
    float xv[16] = {x0.x,x0.y,x0.z,x0.w, x1.x,x1.y,x1.z,x1.w,
                    x2.x,x2.y,x2.z,x2.w, x3.x,x3.y,x3.z,x3.w};
    #pragma unroll
    for (int r=0;r<TN1;r++){
      ag[r] = fmaf(xv[r], wg, ag[r]);
      am[r] = fmaf(xv[r], wm, am[r]);
    }
  }
  float* hp = h_out  + ((size_t)v*N + n0)*H + t;
  float* mp = mlp_out + ((size_t)v*N + n0)*H + t;
  #pragma unroll
  for (int r=0;r<TN1;r++){ hp[(size_t)r*H] = ag[r]; mp[(size_t)r*H] = am[r]; }
}

// ---------------- K1b: e1 = h.a1, e2 = h.a2 per row ----------------
__global__ __launch_bounds__(128) void k1b_e(
    const float* __restrict__ h, const float* __restrict__ a1,
    const float* __restrict__ a2, float* __restrict__ e1, float* __restrict__ e2)
{
  const int v = blockIdx.y, n = blockIdx.x, t = threadIdx.x;
  float hv = h[((size_t)v*N + n)*H + t];
  float p1 = hv * a1[v*H + t];
  float p2 = hv * a2[v*H + t];
  #pragma unroll
  for (int o=32;o>0;o>>=1){ p1 += __shfl_down(p1,o); p2 += __shfl_down(p2,o); }
  __shared__ float s1[2], s2[2];
  if ((t&63)==0){ s1[t>>6]=p1; s2[t>>6]=p2; }
  __syncthreads();
  if (t==0){ e1[(size_t)v*N+n] = s1[0]+s1[1]; e2[(size_t)v*N+n] = s2[0]+s2[1]; }
}

// ---------------- K2: masked graph attention, NO max-subtraction ----------------
// logits e1+e2 are O(+-6) -> exp() safe in fp32; masked weight is exactly 0
// (ref: exp(NEG - max) == 0). One running denom per row, reduced at the end.
#define TN2 16
#define CM 64
__global__ __launch_bounds__(128) void k2_attn(
    const float* __restrict__ h, const int* __restrict__ adj,
    const float* __restrict__ e1g, const float* __restrict__ e2g,
    const float* __restrict__ mlp_out,
    const float* __restrict__ gac_b, const float* __restrict__ mlp_b,
    float* __restrict__ feat)
{
  const int v = blockIdx.y;
  const int n0 = blockIdx.x * TN2;
  const int t = threadIdx.x;
  __shared__ float W[CM][TN2];     // unnormalized softmax weights, [m][r]
  __shared__ float e2s[CM];
  __shared__ float Ssh[TN2];
  float acc[TN2];
  #pragma unroll
  for (int r=0;r<TN2;r++) acc[r]=0.f;
  const int lr = t >> 3, ls = t & 7;      // row lr (16 rows), 8 cols per thread per chunk
  const float e1r = e1g[(size_t)v*N + n0 + lr];
  const int* apb = adj + ((size_t)v*N + n0 + lr)*N + ls*8;
  const float* hp = h + (size_t)v*N*H + t;
  float psum = 0.f;                        // this thread's partial of row lr's denom
  for (int m0=0; m0<N; m0+=CM){
    __syncthreads();                       // protects e2s and W vs previous chunk's readers
    if (t < CM) e2s[t] = e2g[(size_t)v*N + m0 + t];
    __syncthreads();
    const int4* a4 = (const int4*)(apb + m0);
    int4 av0 = a4[0], av1 = a4[1];
    int aa[8] = {av0.x,av0.y,av0.z,av0.w, av1.x,av1.y,av1.z,av1.w};
    #pragma unroll
    for (int i=0;i<8;i++){
      float x = e1r + e2s[ls*8+i];
      x = (x >= 0.f) ? x : 0.25f*x;        // leaky BEFORE mask (matches ref)
      float w = (aa[i] > 0) ? __expf(x) : 0.f;
      W[ls*8+i][lr] = w;
      psum += w;
    }
    __syncthreads();
    const float* hc = hp + (size_t)m0*H;
    for (int m=0;m<CM;m++){
      float hv = hc[(size_t)m*H];          // coalesced across t; L2-resident
      const float4* wp = (const float4*)&W[m][0];   // broadcast LDS read
      float4 w0=wp[0], w1=wp[1], w2=wp[2], w3=wp[3];
      acc[0]  = fmaf(w0.x, hv, acc[0]);  acc[1]  = fmaf(w0.y, hv, acc[1]);
      acc[2]  = fmaf(w0.z, hv, acc[2]);  acc[3]  = fmaf(w0.w, hv, acc[3]);
      acc[4]  = fmaf(w1.x, hv, acc[4]);  acc[5]  = fmaf(w1.y, hv, acc[5]);
      acc[6]  = fmaf(w1.z, hv, acc[6]);  acc[7]  = fmaf(w1.w, hv, acc[7]);
      acc[8]  = fmaf(w2.x, hv, acc[8]);  acc[9]  = fmaf(w2.y, hv, acc[9]);
      acc[10] = fmaf(w2.z, hv, acc[10]); acc[11] = fmaf(w2.w, hv, acc[11]);
      acc[12] = fmaf(w3.x, hv, acc[12]); acc[13] = fmaf(w3.y, hv, acc[13]);
      acc[14] = fmaf(w3.z, hv, acc[14]); acc[15] = fmaf(w3.w, hv, acc[15]);
    }
  }
  // reduce psum across the 8 lanes owning row lr (contiguous lanes within a wave)
  psum += __shfl_xor(psum, 1);
  psum += __shfl_xor(psum, 2);
  psum += __shfl_xor(psum, 4);
  if (ls == 0) Ssh[lr] = psum;
  __syncthreads();
  const float gb = gac_b[v*H + t];
  const float mb = mlp_b[v*H + t];
  const float* mo = mlp_out + ((size_t)v*N + n0)*H + t;
  float* fo = feat + ((size_t)v*N + n0)*H + t;
  #pragma unroll
  for (int r=0;r<TN2;r++){
    float x = acc[r] / Ssh[r] + gb;
    x = (x >= 0.f) ? x : 0.25f*x;
    fo[(size_t)r*H] = x + mo[(size_t)r*H] + mb;
  }
}

// ---------------- K3: per-node HxH outer-product attention + fc + conf gate ----------------
// logits qi*K_o are O(+-2) after the 1/sqrt(128) scale -> exp() safe, no max needed.
#define TN3 8
__global__ __launch_bounds__(128) void k3_sgfe(
    const float* __restrict__ feat,
    const float* __restrict__ qw, const float* __restrict__ qb,
    const float* __restrict__ kw, const float* __restrict__ kb,
    const float* __restrict__ vw, const float* __restrict__ vb,
    const float* __restrict__ fcw, const float* __restrict__ fcb,
    const float* __restrict__ confw, const float* __restrict__ confb,
    float* __restrict__ feat2)
{
  const int v = blockIdx.y;
  const int n0 = blockIdx.x * TN3;
  const int t = threadIdx.x;
  __shared__ float fsT[H][TN3];
  __shared__ float Ks[H], Vs[H], As[H];
  __shared__ float rbuf[2];
  const float* fp = feat + ((size_t)v*N + n0)*H + t;
  #pragma unroll
  for (int r=0;r<TN3;r++) fsT[t][r] = fp[(size_t)r*H];
  __syncthreads();
  const float* qwp = qw + (size_t)v*H*H + t;
  const float* kwp = kw + (size_t)v*H*H + t;
  const float* vwp = vw + (size_t)v*H*H + t;
  float Qr[TN3], Kr[TN3], Vr[TN3];
  {
    const float qbv = qb[v*H+t], kbv = kb[v*H+t], vbv = vb[v*H+t];
    #pragma unroll
    for (int r=0;r<TN3;r++){ Qr[r]=qbv; Kr[r]=kbv; Vr[r]=vbv; }
  }
  for (int i=0;i<H;i++){   // one weight sweep computes Q,K,V for all 8 rows
    float wq = qwp[(size_t)i*H];
    float wk = kwp[(size_t)i*H];
    float wv = vwp[(size_t)i*H];
    const float4* f4 = (const float4*)&fsT[i][0];
    float4 f0=f4[0], f1=f4[1];
    float fv[8] = {f0.x,f0.y,f0.z,f0.w, f1.x,f1.y,f1.z,f1.w};
    #pragma unroll
    for (int r=0;r<TN3;r++){
      Qr[r] = fmaf(fv[r], wq, Qr[r]);
      Kr[r] = fmaf(fv[r], wk, Kr[r]);
      Vr[r] = fmaf(fv[r], wv, Vr[r]);
    }
  }
  const float invs = 0.08838834764831845f;  // 1/sqrt(128)
  const float* fcwp = fcw + (size_t)v*H*H + t;
  const float fcbv = fcb[v*H+t];
  const float cwv = confw[v*H+t];
  const float cbv = confb[v];
  float* f2p = feat2 + ((size_t)v*N + n0)*H + t;
  for (int r=0;r<TN3;r++){
    Ks[t] = Kr[r]; Vs[t] = Vr[r];
    __syncthreads();                        // A: Ks/Vs visible
    const float qi = Qr[r]*invs;
    float s=0.f, a=0.f;
    for (int o=0;o<H;o++){
      float e = __expf(qi * Ks[o]);
      s += e;
      a = fmaf(e, Vs[o], a);
    }
    As[t] = a/s;
    __syncthreads();                        // B: As visible
    float g = fcbv;
    for (int i=0;i<H;i++) g = fmaf(As[i], fcwp[(size_t)i*H], g);
    g = fmaxf(g, 0.f);
    float p = g*cwv;
    #pragma unroll
    for (int o=32;o>0;o>>=1) p += __shfl_down(p,o);
    if ((t&63)==0) rbuf[t>>6]=p;
    __syncthreads();                        // C: rbuf visible
    const float conf = rbuf[0]+rbuf[1]+cbv;
    f2p[(size_t)r*H] = g*conf;
    __syncthreads();                        // D: done before next iter rewrites Ks/Vs/As/rbuf
  }
}

// ---------------- K4: final classifier [N, V*H] @ [V*H, C] ----------------
__global__ __launch_bounds__(64) void k4_cls(
    const float* __restrict__ feat2,
    const float* __restrict__ mm_w, const float* __restrict__ mm_b,
    float* __restrict__ out)
{
  const int n = blockIdx.x, t = threadIdx.x;
  float a[C] = {0,0,0,0,0};
  for (int j=t; j<V*H; j+=64){
    int vv = j >> 7, hh = j & (H-1);
    float f = feat2[((size_t)vv*N + n)*H + hh];
    #pragma unroll
    for (int c=0;c<C;c++) a[c] = fmaf(f, mm_w[j*C+c], a[c]);
  }
  #pragma unroll
  for (int c=0;c<C;c++){
    #pragma unroll
    for (int o=32;o>0;o>>=1) a[c] += __shfl_down(a[c],o);
  }
  if (t==0){
    #pragma unroll
    for (int c=0;c<C;c++) out[(size_t)n*C+c] = a[c] + mm_b[c];
  }
}

extern "C" void kernel_launch(void* const* d_in, const int* in_sizes, int n_in,
                              void* d_out, int out_size, void* d_ws, size_t ws_size,
                              hipStream_t stream)
{
  (void)in_sizes; (void)n_in; (void)out_size; (void)ws_size;
  const float* data  = (const float*)d_in[0];
  const int*   adj   = (const int*)d_in[1];
  const float* gac_w = (const float*)d_in[2];
  const float* gac_b = (const float*)d_in[3];
  const float* a1    = (const float*)d_in[4];
  const float* a2    = (const float*)d_in[5];
  const float* mlp_w = (const float*)d_in[6];
  const float* mlp_b = (const float*)d_in[7];
  const float* q_w   = (const float*)d_in[8];
  const float* q_b   = (const float*)d_in[9];
  const float* k_w   = (const float*)d_in[10];
  const float* k_b   = (const float*)d_in[11];
  const float* v_w   = (const float*)d_in[12];
  const float* v_b   = (const float*)d_in[13];
  const float* fc_w  = (const float*)d_in[14];
  const float* fc_b  = (const float*)d_in[15];
  const float* cw    = (const float*)d_in[16];
  const float* cb    = (const float*)d_in[17];
  const float* mm_w  = (const float*)d_in[18];
  const float* mm_b  = (const float*)d_in[19];

  float* ws = (float*)d_ws;
  const size_t VNH = (size_t)V*N*H;
  float* h     = ws;
  float* mlp   = ws + VNH;
  float* e1    = ws + 2*VNH;
  float* e2    = e1 + (size_t)V*N;
  float* feat  = e2 + (size_t)V*N;
  float* feat2 = feat + VNH;

  k1_gemm<<<dim3(N/TN1, V), 128, 0, stream>>>(data, gac_w, mlp_w, h, mlp);
  k1b_e <<<dim3(N, V),      128, 0, stream>>>(h, a1, a2, e1, e2);
  k2_attn<<<dim3(N/TN2, V), 128, 0, stream>>>(h, adj, e1, e2, mlp, gac_b, mlp_b, feat);
  k3_sgfe<<<dim3(N/TN3, V), 128, 0, stream>>>(feat, q_w, q_b, k_w, k_b, v_w, v_b,
                                              fc_w, fc_b, cw, cb, feat2);
  k4_cls<<<dim3(N),          64, 0, stream>>>(feat2, mm_w, mm_b, (float*)d_out);
}

// Round 4
// 745.604 us; speedup vs baseline: 1.1529x; 1.1529x over previous
//
#include <hip/hip_runtime.h>
#include <hip/hip_bf16.h>

#define V 3
#define N 4096
#define D 512
#define H 128
#define C 5

// ---------------- K1: h = data@gac_w, mlp = data@mlp_w (split-D, 256 thr) ----------------
#define TN1 16
__global__ __launch_bounds__(256, 4) void k1_gemm(
    const float* __restrict__ data,
    const float* __restrict__ gac_w,
    const float* __restrict__ mlp_w,
    float* __restrict__ h_out, float* __restrict__ mlp_out)
{
  const int v = blockIdx.y;
  const int n0 = blockIdx.x * TN1;
  const int t = threadIdx.x;
  const int half = t >> 7, tt = t & 127;   // half 0: d 0..255, half 1: d 256..511
  __shared__ float ds[D][20];              // transposed data tile; 40 KB
  float* comb = &ds[0][0];                 // aliased post-compute: [2][TN1][H] = 16 KB
  const float* dp = data + ((size_t)v*N + n0)*D;
  for (int j = t; j < TN1*D; j += 256){
    int r = j >> 9, d = j & (D-1);
    ds[d][r] = dp[(size_t)r*D + d];
  }
  __syncthreads();
  float ag[TN1], am[TN1];
  #pragma unroll
  for (int r=0;r<TN1;r++){ ag[r]=0.f; am[r]=0.f; }
  const int d0 = half*256;
  const float* gw = gac_w + (size_t)v*D*H + tt;
  const float* mw = mlp_w + (size_t)v*D*H + tt;
  for (int d=d0; d<d0+256; d++){
    float wg = gw[(size_t)d*H];
    float wm = mw[(size_t)d*H];
    const float4* p = (const float4*)&ds[d][0];
    float4 x0=p[0], x1=p[1], x2=p[2], x3=p[3];
    float xv[16] = {x0.x,x0.y,x0.z,x0.w, x1.x,x1.y,x1.z,x1.w,
                    x2.x,x2.y,x2.z,x2.w, x3.x,x3.y,x3.z,x3.w};
    #pragma unroll
    for (int r=0;r<TN1;r++){
      ag[r] = fmaf(xv[r], wg, ag[r]);
      am[r] = fmaf(xv[r], wm, am[r]);
    }
  }
  __syncthreads();                         // all ds reads done; safe to alias comb
  if (half == 1){
    #pragma unroll
    for (int r=0;r<TN1;r++){
      comb[r*H + tt]          = ag[r];
      comb[TN1*H + r*H + tt]  = am[r];
    }
  }
  __syncthreads();
  if (half == 0){
    float* hp = h_out   + ((size_t)v*N + n0)*H + tt;
    float* mp = mlp_out + ((size_t)v*N + n0)*H + tt;
    #pragma unroll
    for (int r=0;r<TN1;r++){
      hp[(size_t)r*H] = ag[r] + comb[r*H + tt];
      mp[(size_t)r*H] = am[r] + comb[TN1*H + r*H + tt];
    }
  }
}

// ---------------- K1b: e1 = h.a1, e2 = h.a2 per row ----------------
__global__ __launch_bounds__(128) void k1b_e(
    const float* __restrict__ h, const float* __restrict__ a1,
    const float* __restrict__ a2, float* __restrict__ e1, float* __restrict__ e2)
{
  const int v = blockIdx.y, n = blockIdx.x, t = threadIdx.x;
  float hv = h[((size_t)v*N + n)*H + t];
  float p1 = hv * a1[v*H + t];
  float p2 = hv * a2[v*H + t];
  #pragma unroll
  for (int o=32;o>0;o>>=1){ p1 += __shfl_down(p1,o); p2 += __shfl_down(p2,o); }
  __shared__ float s1[2], s2[2];
  if ((t&63)==0){ s1[t>>6]=p1; s2[t>>6]=p2; }
  __syncthreads();
  if (t==0){ e1[(size_t)v*N+n] = s1[0]+s1[1]; e2[(size_t)v*N+n] = s2[0]+s2[1]; }
}

// ---------------- K2: masked graph attention, in-block split-K over 8 waves ----------------
// Each wave independently processes interleaved 64-col chunks with a PRIVATE LDS
// weight buffer (no inter-wave deps in main loop). No max-subtraction: logits
// e1+e2 are O(+-6), masked weights exactly 0 (ref: exp(NEG-max)==0).
#define TN2 16
#define CM 64
#define KW 8
__global__ __launch_bounds__(512, 4) void k2_attn(
    const float* __restrict__ h, const int* __restrict__ adj,
    const float* __restrict__ e1g, const float* __restrict__ e2g,
    const float* __restrict__ mlp_out,
    const float* __restrict__ gac_b, const float* __restrict__ mlp_b,
    float* __restrict__ feat)
{
  const int v = blockIdx.y;
  const int n0 = blockIdx.x * TN2;
  const int t = threadIdx.x;
  const int w = t >> 6, lane = t & 63;
  __shared__ float Wb[KW][CM][TN2];        // 32 KB, wave-private slices
  __shared__ float pden[KW][TN2];          // per-wave per-row partial denominators
  float* AccS = &Wb[0][0][0];              // aliased combine area: [4][TN2][H] = 32 KB

  float acc[TN2][2];
  #pragma unroll
  for (int r=0;r<TN2;r++){ acc[r][0]=0.f; acc[r][1]=0.f; }
  const int lr = lane >> 2, ls = lane & 3;   // 4 lanes per tile-row, 16 cols each
  const float e1r = e1g[(size_t)v*N + n0 + lr];
  const int* aprow = adj + ((size_t)v*N + n0 + lr)*N;
  const float* hb = h + (size_t)v*N*H + 2*lane;
  float psum = 0.f;

  for (int j=0; j<N/(CM*KW); j++){           // 8 chunks per wave
    const int m0 = (w + j*KW) * CM;
    float e2v = e2g[(size_t)v*N + m0 + lane];          // lane's e2 value
    const int4* a4 = (const int4*)(aprow + m0 + ls*16);
    int4 b0=a4[0], b1=a4[1], b2=a4[2], b3=a4[3];
    int aa[16] = {b0.x,b0.y,b0.z,b0.w, b1.x,b1.y,b1.z,b1.w,
                  b2.x,b2.y,b2.z,b2.w, b3.x,b3.y,b3.z,b3.w};
    #pragma unroll
    for (int i=0;i<16;i++){
      float e2i = __shfl(e2v, ls*16 + i);
      float x = e1r + e2i;
      x = (x >= 0.f) ? x : 0.25f*x;          // leaky BEFORE mask (matches ref)
      float ww = (aa[i] > 0) ? __expf(x) : 0.f;
      Wb[w][ls*16+i][lr] = ww;
      psum += ww;
    }
    __syncthreads();   // LDS visibility (same-wave producer/consumer; waves have equal work)
    const float* hc = hb + (size_t)m0*H;
    #pragma unroll 4
    for (int m=0;m<CM;m++){
      float2 hv = *(const float2*)(hc + (size_t)m*H);  // wave reads full 512B h row
      const float4* wp = (const float4*)&Wb[w][m][0];  // broadcast (all lanes same addr)
      float4 w0=wp[0], w1=wp[1], w2=wp[2], w3=wp[3];
      acc[0][0]=fmaf(w0.x,hv.x,acc[0][0]);   acc[0][1]=fmaf(w0.x,hv.y,acc[0][1]);
      acc[1][0]=fmaf(w0.y,hv.x,acc[1][0]);   acc[1][1]=fmaf(w0.y,hv.y,acc[1][1]);
      acc[2][0]=fmaf(w0.z,hv.x,acc[2][0]);   acc[2][1]=fmaf(w0.z,hv.y,acc[2][1]);
      acc[3][0]=fmaf(w0.w,hv.x,acc[3][0]);   acc[3][1]=fmaf(w0.w,hv.y,acc[3][1]);
      acc[4][0]=fmaf(w1.x,hv.x,acc[4][0]);   acc[4][1]=fmaf(w1.x,hv.y,acc[4][1]);
      acc[5][0]=fmaf(w1.y,hv.x,acc[5][0]);   acc[5][1]=fmaf(w1.y,hv.y,acc[5][1]);
      acc[6][0]=fmaf(w1.z,hv.x,acc[6][0]);   acc[6][1]=fmaf(w1.z,hv.y,acc[6][1]);
      acc[7][0]=fmaf(w1.w,hv.x,acc[7][0]);   acc[7][1]=fmaf(w1.w,hv.y,acc[7][1]);
      acc[8][0]=fmaf(w2.x,hv.x,acc[8][0]);   acc[8][1]=fmaf(w2.x,hv.y,acc[8][1]);
      acc[9][0]=fmaf(w2.y,hv.x,acc[9][0]);   acc[9][1]=fmaf(w2.y,hv.y,acc[9][1]);
      acc[10][0]=fmaf(w2.z,hv.x,acc[10][0]); acc[10][1]=fmaf(w2.z,hv.y,acc[10][1]);
      acc[11][0]=fmaf(w2.w,hv.x,acc[11][0]); acc[11][1]=fmaf(w2.w,hv.y,acc[11][1]);
      acc[12][0]=fmaf(w3.x,hv.x,acc[12][0]); acc[12][1]=fmaf(w3.x,hv.y,acc[12][1]);
      acc[13][0]=fmaf(w3.y,hv.x,acc[13][0]); acc[13][1]=fmaf(w3.y,hv.y,acc[13][1]);
      acc[14][0]=fmaf(w3.z,hv.x,acc[14][0]); acc[14][1]=fmaf(w3.z,hv.y,acc[14][1]);
      acc[15][0]=fmaf(w3.w,hv.x,acc[15][0]); acc[15][1]=fmaf(w3.w,hv.y,acc[15][1]);
    }
    __syncthreads();   // wave done reading its Wb slice before next j overwrites it
  }
  // per-wave row denominators: reduce over the 4 lanes of each tile-row
  psum += __shfl_xor(psum, 1);
  psum += __shfl_xor(psum, 2);
  if (ls == 0) pden[w][lr] = psum;
  __syncthreads();                                    // B1: loop done; pden visible
  // tree-combine 8 wave-partials; AccS[wq][r][c], c = 2*lane+{0,1}
  if (w >= 4){
    #pragma unroll
    for (int r=0;r<TN2;r++)
      *(float2*)&AccS[(w-4)*TN2*H + r*H + 2*lane] = make_float2(acc[r][0], acc[r][1]);
  }
  __syncthreads();                                    // B2
  if (w < 4){
    #pragma unroll
    for (int r=0;r<TN2;r++){
      float2 p = *(float2*)&AccS[w*TN2*H + r*H + 2*lane];
      acc[r][0] += p.x; acc[r][1] += p.y;
    }
  }
  __syncthreads();                                    // B3
  if (w == 2 || w == 3){
    #pragma unroll
    for (int r=0;r<TN2;r++)
      *(float2*)&AccS[(w-2)*TN2*H + r*H + 2*lane] = make_float2(acc[r][0], acc[r][1]);
  }
  __syncthreads();                                    // B4
  if (w < 2){
    #pragma unroll
    for (int r=0;r<TN2;r++){
      float2 p = *(float2*)&AccS[w*TN2*H + r*H + 2*lane];
      acc[r][0] += p.x; acc[r][1] += p.y;
    }
  }
  __syncthreads();                                    // B5
  if (w == 1){
    #pragma unroll
    for (int r=0;r<TN2;r++)
      *(float2*)&AccS[r*H + 2*lane] = make_float2(acc[r][0], acc[r][1]);
  }
  __syncthreads();                                    // B6
  if (w == 0){
    const int c0 = 2*lane;
    float2 gb = *(const float2*)&gac_b[v*H + c0];
    float2 mb = *(const float2*)&mlp_b[v*H + c0];
    const float* mo = mlp_out + ((size_t)v*N + n0)*H + c0;
    float* fo = feat + ((size_t)v*N + n0)*H + c0;
    #pragma unroll
    for (int r=0;r<TN2;r++){
      float2 p = *(float2*)&AccS[r*H + c0];
      float num0 = acc[r][0] + p.x, num1 = acc[r][1] + p.y;
      float den = 0.f;
      #pragma unroll
      for (int k=0;k<KW;k++) den += pden[k][r];       // broadcast LDS reads
      float2 mo2 = *(const float2*)&mo[(size_t)r*H];
      float x0 = num0/den + gb.x;  x0 = (x0>=0.f)?x0:0.25f*x0;
      float x1 = num1/den + gb.y;  x1 = (x1>=0.f)?x1:0.25f*x1;
      *(float2*)&fo[(size_t)r*H] = make_float2(x0 + mo2.x + mb.x, x1 + mo2.y + mb.y);
    }
  }
}

// ---------------- K3: per-node HxH outer-product attention + fc + conf gate ----------------
#define TN3 8
__global__ __launch_bounds__(128) void k3_sgfe(
    const float* __restrict__ feat,
    const float* __restrict__ qw, const float* __restrict__ qb,
    const float* __restrict__ kw, const float* __restrict__ kb,
    const float* __restrict__ vw, const float* __restrict__ vb,
    const float* __restrict__ fcw, const float* __restrict__ fcb,
    const float* __restrict__ confw, const float* __restrict__ confb,
    float* __restrict__ feat2)
{
  const int v = blockIdx.y;
  const int n0 = blockIdx.x * TN3;
  const int t = threadIdx.x;
  __shared__ float fsT[H][TN3];
  __shared__ float Ks[H], Vs[H], As[H];
  __shared__ float rbuf[2];
  const float* fp = feat + ((size_t)v*N + n0)*H + t;
  #pragma unroll
  for (int r=0;r<TN3;r++) fsT[t][r] = fp[(size_t)r*H];
  __syncthreads();
  const float* qwp = qw + (size_t)v*H*H + t;
  const float* kwp = kw + (size_t)v*H*H + t;
  const float* vwp = vw + (size_t)v*H*H + t;
  float Qr[TN3], Kr[TN3], Vr[TN3];
  {
    const float qbv = qb[v*H+t], kbv = kb[v*H+t], vbv = vb[v*H+t];
    #pragma unroll
    for (int r=0;r<TN3;r++){ Qr[r]=qbv; Kr[r]=kbv; Vr[r]=vbv; }
  }
  for (int i=0;i<H;i++){
    float wq = qwp[(size_t)i*H];
    float wk = kwp[(size_t)i*H];
    float wv = vwp[(size_t)i*H];
    const float4* f4 = (const float4*)&fsT[i][0];
    float4 f0=f4[0], f1=f4[1];
    float fv[8] = {f0.x,f0.y,f0.z,f0.w, f1.x,f1.y,f1.z,f1.w};
    #pragma unroll
    for (int r=0;r<TN3;r++){
      Qr[r] = fmaf(fv[r], wq, Qr[r]);
      Kr[r] = fmaf(fv[r], wk, Kr[r]);
      Vr[r] = fmaf(fv[r], wv, Vr[r]);
    }
  }
  const float invs = 0.08838834764831845f;  // 1/sqrt(128)
  const float* fcwp = fcw + (size_t)v*H*H + t;
  const float fcbv = fcb[v*H+t];
  const float cwv = confw[v*H+t];
  const float cbv = confb[v];
  float* f2p = feat2 + ((size_t)v*N + n0)*H + t;
  for (int r=0;r<TN3;r++){
    Ks[t] = Kr[r]; Vs[t] = Vr[r];
    __syncthreads();
    const float qi = Qr[r]*invs;
    float s=0.f, a=0.f;
    for (int o=0;o<H;o++){
      float e = __expf(qi * Ks[o]);
      s += e;
      a = fmaf(e, Vs[o], a);
    }
    As[t] = a/s;
    __syncthreads();
    float g = fcbv;
    for (int i=0;i<H;i++) g = fmaf(As[i], fcwp[(size_t)i*H], g);
    g = fmaxf(g, 0.f);
    float p = g*cwv;
    #pragma unroll
    for (int o=32;o>0;o>>=1) p += __shfl_down(p,o);
    if ((t&63)==0) rbuf[t>>6]=p;
    __syncthreads();
    const float conf = rbuf[0]+rbuf[1]+cbv;
    f2p[(size_t)r*H] = g*conf;
    __syncthreads();
  }
}

// ---------------- K4: final classifier [N, V*H] @ [V*H, C] ----------------
__global__ __launch_bounds__(64) void k4_cls(
    const float* __restrict__ feat2,
    const float* __restrict__ mm_w, const float* __restrict__ mm_b,
    float* __restrict__ out)
{
  const int n = blockIdx.x, t = threadIdx.x;
  float a[C] = {0,0,0,0,0};
  for (int j=t; j<V*H; j+=64){
    int vv = j >> 7, hh = j & (H-1);
    float f = feat2[((size_t)vv*N + n)*H + hh];
    #pragma unroll
    for (int c=0;c<C;c++) a[c] = fmaf(f, mm_w[j*C+c], a[c]);
  }
  #pragma unroll
  for (int c=0;c<C;c++){
    #pragma unroll
    for (int o=32;o>0;o>>=1) a[c] += __shfl_down(a[c],o);
  }
  if (t==0){
    #pragma unroll
    for (int c=0;c<C;c++) out[(size_t)n*C+c] = a[c] + mm_b[c];
  }
}

extern "C" void kernel_launch(void* const* d_in, const int* in_sizes, int n_in,
                              void* d_out, int out_size, void* d_ws, size_t ws_size,
                              hipStream_t stream)
{
  (void)in_sizes; (void)n_in; (void)out_size; (void)ws_size;
  const float* data  = (const float*)d_in[0];
  const int*   adj   = (const int*)d_in[1];
  const float* gac_w = (const float*)d_in[2];
  const float* gac_b = (const float*)d_in[3];
  const float* a1    = (const float*)d_in[4];
  const float* a2    = (const float*)d_in[5];
  const float* mlp_w = (const float*)d_in[6];
  const float* mlp_b = (const float*)d_in[7];
  const float* q_w   = (const float*)d_in[8];
  const float* q_b   = (const float*)d_in[9];
  const float* k_w   = (const float*)d_in[10];
  const float* k_b   = (const float*)d_in[11];
  const float* v_w   = (const float*)d_in[12];
  const float* v_b   = (const float*)d_in[13];
  const float* fc_w  = (const float*)d_in[14];
  const float* fc_b  = (const float*)d_in[15];
  const float* cw    = (const float*)d_in[16];
  const float* cb    = (const float*)d_in[17];
  const float* mm_w  = (const float*)d_in[18];
  const float* mm_b  = (const float*)d_in[19];

  float* ws = (float*)d_ws;
  const size_t VNH = (size_t)V*N*H;
  float* h     = ws;
  float* mlp   = ws + VNH;
  float* e1    = ws + 2*VNH;
  float* e2    = e1 + (size_t)V*N;
  float* feat  = e2 + (size_t)V*N;
  float* feat2 = feat + VNH;

  k1_gemm<<<dim3(N/TN1, V), 256, 0, stream>>>(data, gac_w, mlp_w, h, mlp);
  k1b_e <<<dim3(N, V),      128, 0, stream>>>(h, a1, a2, e1, e2);
  k2_attn<<<dim3(N/TN2, V), 512, 0, stream>>>(h, adj, e1, e2, mlp, gac_b, mlp_b, feat);
  k3_sgfe<<<dim3(N/TN3, V), 128, 0, stream>>>(feat, q_w, q_b, k_w, k_b, v_w, v_b,
                                              fc_w, fc_b, cw, cb, feat2);
  k4_cls<<<dim3(N),          64, 0, stream>>>(feat2, mm_w, mm_b, (float*)d_out);
}

// Round 5
// 506.206 us; speedup vs baseline: 1.6981x; 1.4729x over previous
//
#include <hip/hip_runtime.h>
#include <hip/hip_bf16.h>

#define V 3
#define N 4096
#define D 512
#define H 128
#define C 5

typedef short short8 __attribute__((ext_vector_type(8)));
typedef float floatx4 __attribute__((ext_vector_type(4)));

__device__ __forceinline__ unsigned short f2bf(float f){
  __hip_bfloat16 h = __float2bfloat16(f);
  return *reinterpret_cast<unsigned short*>(&h);
}

// ---------------- K1: h = data@gac_w (-> hT bf16 [V][H][N]), mlp = data@mlp_w,
// ----------------     e1 = h.a1, e2 = h.a2 (K1b folded in) ----------------
#define TN1 16
__global__ __launch_bounds__(256) void k1_gemm(
    const float* __restrict__ data,
    const float* __restrict__ gac_w,
    const float* __restrict__ mlp_w,
    const float* __restrict__ a1, const float* __restrict__ a2,
    unsigned short* __restrict__ hT, float* __restrict__ mlp_out,
    float* __restrict__ e1, float* __restrict__ e2)
{
  const int v = blockIdx.y;
  const int n0 = blockIdx.x * TN1;
  const int t = threadIdx.x;
  const int half = t >> 7, tt = t & 127;   // half 0: d 0..255, half 1: d 256..511
  __shared__ float ds[D][20];              // transposed data tile; 40 KB
  __shared__ float epart[2][2][TN1];       // e1/e2 wave partials
  float* comb = &ds[0][0];                 // aliased post-compute: [2][TN1][H]
  const float* dp = data + ((size_t)v*N + n0)*D;
  for (int j = t; j < TN1*D; j += 256){
    int r = j >> 9, d = j & (D-1);
    ds[d][r] = dp[(size_t)r*D + d];
  }
  __syncthreads();
  float ag[TN1], am[TN1];
  #pragma unroll
  for (int r=0;r<TN1;r++){ ag[r]=0.f; am[r]=0.f; }
  const int d0 = half*256;
  const float* gw = gac_w + (size_t)v*D*H + tt;
  const float* mw = mlp_w + (size_t)v*D*H + tt;
  for (int d=d0; d<d0+256; d++){
    float wg = gw[(size_t)d*H];
    float wm = mw[(size_t)d*H];
    const float4* p = (const float4*)&ds[d][0];
    float4 x0=p[0], x1=p[1], x2=p[2], x3=p[3];
    float xv[16] = {x0.x,x0.y,x0.z,x0.w, x1.x,x1.y,x1.z,x1.w,
                    x2.x,x2.y,x2.z,x2.w, x3.x,x3.y,x3.z,x3.w};
    #pragma unroll
    for (int r=0;r<TN1;r++){
      ag[r] = fmaf(xv[r], wg, ag[r]);
      am[r] = fmaf(xv[r], wm, am[r]);
    }
  }
  __syncthreads();                         // all ds reads done; safe to alias comb
  if (half == 1){
    #pragma unroll
    for (int r=0;r<TN1;r++){
      comb[r*H + tt]          = ag[r];
      comb[TN1*H + r*H + tt]  = am[r];
    }
  }
  __syncthreads();
  if (half == 0){
    float* mp = mlp_out + ((size_t)v*N + n0)*H + tt;
    unsigned short pk[TN1];
    const float a1v = a1[v*H + tt], a2v = a2[v*H + tt];
    #pragma unroll
    for (int r=0;r<TN1;r++){
      ag[r] += comb[r*H + tt];
      am[r] += comb[TN1*H + r*H + tt];
      mp[(size_t)r*H] = am[r];
      pk[r] = f2bf(ag[r]);
    }
    uint4* hp = (uint4*)(hT + ((size_t)v*H + tt)*N + n0);   // transposed bf16 h
    hp[0] = *(uint4*)&pk[0];
    hp[1] = *(uint4*)&pk[8];
    // e1/e2: reduce ag[r]*a1/a2 across the 128 half-0 threads (waves 0,1)
    #pragma unroll
    for (int r=0;r<TN1;r++){
      float s1 = ag[r]*a1v, s2 = ag[r]*a2v;
      #pragma unroll
      for (int o=32;o>0;o>>=1){ s1 += __shfl_down(s1,o); s2 += __shfl_down(s2,o); }
      if ((tt&63)==0){ epart[0][tt>>6][r]=s1; epart[1][tt>>6][r]=s2; }
    }
  }
  __syncthreads();
  if (t < TN1)            e1[(size_t)v*N + n0 + t]        = epart[0][0][t]    + epart[0][1][t];
  else if (t < 2*TN1)     e2[(size_t)v*N + n0 + (t-TN1)]  = epart[1][0][t-TN1]+ epart[1][1][t-TN1];
}

// ---------------- K2: masked graph attention via bf16 MFMA ----------------
// D[r][c] = sum_m W[m][r] * h[m][c]; A = W^T (16 x K), B = h (K x 128, from hT).
// A produced per 128-K chunk in fragment order (conflict-free b128 reads);
// B-fragments straight from global hT. No max-subtraction (logits O(+-6),
// masked weights exactly 0 -> matches ref exp(NEG-max)==0).
#define KC 128
__global__ __launch_bounds__(512) void k2_attn(
    const unsigned short* __restrict__ hT, const int* __restrict__ adj,
    const float* __restrict__ e1g, const float* __restrict__ e2g,
    const float* __restrict__ mlp_out,
    const float* __restrict__ gac_b, const float* __restrict__ mlp_b,
    float* __restrict__ feat)
{
  const int v = blockIdx.y;
  const int n0 = blockIdx.x * 16;
  const int t = threadIdx.x;
  const int w = t >> 6, lane = t & 63;
  __shared__ unsigned short Afrag[4][64][8];   // [kstep][lane][j], 4 KB
  __shared__ float pden_l[8][16];              // per-wave per-row denom partials

  // producer mapping: r = t&15, sm = t>>4 (0..31), m = 4*sm + jj
  const int pr = t & 15, sm = t >> 4;
  const int p_ks   = sm >> 3;
  const int p_lane = pr + 16*((sm>>1)&3);
  const int p_j0   = 4*(sm&1);
  const float e1r = e1g[(size_t)v*N + n0 + pr];
  const int* aprow = adj + ((size_t)v*N + n0 + pr)*N;
  float psum = 0.f;

  // consumer setup: wave w owns cols w*16 .. w*16+15
  const int col = w*16 + (lane & 15);
  const unsigned short* bcol = hT + ((size_t)v*H + col)*N + ((lane>>4)*8);
  floatx4 acc = {0.f, 0.f, 0.f, 0.f};

  for (int m0 = 0; m0 < N; m0 += KC){
    // ---- produce A (bf16 W^T) in fragment order ----
    const float4 e2v = *(const float4*)(e2g + (size_t)v*N + m0 + 4*sm);
    const int4  av  = *(const int4*)(aprow + m0 + 4*sm);
    float e2a[4] = {e2v.x, e2v.y, e2v.z, e2v.w};
    int   aa[4]  = {av.x, av.y, av.z, av.w};
    unsigned int pk[2];
    unsigned short us[4];
    #pragma unroll
    for (int jj=0;jj<4;jj++){
      float x = e1r + e2a[jj];
      x = (x >= 0.f) ? x : 0.25f*x;            // leaky BEFORE mask (matches ref)
      float wv = (aa[jj] > 0) ? __expf(x) : 0.f;
      psum += wv;
      us[jj] = f2bf(wv);
    }
    pk[0] = (unsigned int)us[0] | ((unsigned int)us[1] << 16);
    pk[1] = (unsigned int)us[2] | ((unsigned int)us[3] << 16);
    *(uint2*)&Afrag[p_ks][p_lane][p_j0] = make_uint2(pk[0], pk[1]);
    __syncthreads();
    // ---- MFMA over the 4 k-steps of this chunk ----
    #pragma unroll
    for (int ks=0; ks<4; ks++){
      short8 a8 = *(const short8*)&Afrag[ks][lane][0];
      short8 b8 = *(const short8*)(bcol + m0 + ks*32);
      acc = __builtin_amdgcn_mfma_f32_16x16x32_bf16(a8, b8, acc, 0, 0, 0);
    }
    __syncthreads();
  }
  // denominators: threads with same r are lanes {r, r+16, r+32, r+48} per wave
  psum += __shfl_down(psum, 32);
  psum += __shfl_down(psum, 16);
  if (lane < 16) pden_l[w][lane] = psum;
  __syncthreads();
  // epilogue: D[row][col], row = (lane>>4)*4 + reg, col as above
  const float gb = gac_b[v*H + col];
  const float mb = mlp_b[v*H + col];
  #pragma unroll
  for (int reg=0; reg<4; reg++){
    const int row = (lane>>4)*4 + reg;
    float den = 0.f;
    #pragma unroll
    for (int k=0;k<8;k++) den += pden_l[k][row];
    float x = acc[reg]/den + gb;
    x = (x >= 0.f) ? x : 0.25f*x;
    const size_t idx = ((size_t)v*N + n0 + row)*H + col;
    feat[idx] = x + mlp_out[idx] + mb;
  }
}

// ---------------- K3: per-node HxH outer-product attention + fc + conf gate ----------------
#define TN3 8
__global__ __launch_bounds__(128) void k3_sgfe(
    const float* __restrict__ feat,
    const float* __restrict__ qw, const float* __restrict__ qb,
    const float* __restrict__ kw, const float* __restrict__ kb,
    const float* __restrict__ vw, const float* __restrict__ vb,
    const float* __restrict__ fcw, const float* __restrict__ fcb,
    const float* __restrict__ confw, const float* __restrict__ confb,
    float* __restrict__ feat2)
{
  const int v = blockIdx.y;
  const int n0 = blockIdx.x * TN3;
  const int t = threadIdx.x;
  const int W = t >> 6, lane = t & 63;
  __shared__ float fsT[H][12];             // feat tile transposed, padded
  __shared__ float Qs[TN3][H];
  __shared__ float2 KVs[TN3][H];
  __shared__ float As2T[H][12];            // agg, [dim][node], padded
  __shared__ float rbuf2[TN3][2];
  const float* fp = feat + ((size_t)v*N + n0)*H + t;
  #pragma unroll
  for (int r=0;r<TN3;r++) fsT[t][r] = fp[(size_t)r*H];
  __syncthreads();
  const float* qwp = qw + (size_t)v*H*H + t;
  const float* kwp = kw + (size_t)v*H*H + t;
  const float* vwp = vw + (size_t)v*H*H + t;
  float Qr[TN3], Kr[TN3], Vr[TN3];
  {
    const float qbv = qb[v*H+t], kbv = kb[v*H+t], vbv = vb[v*H+t];
    #pragma unroll
    for (int r=0;r<TN3;r++){ Qr[r]=qbv; Kr[r]=kbv; Vr[r]=vbv; }
  }
  for (int i=0;i<H;i++){   // one weight sweep computes Q,K,V for all 8 nodes
    float wq = qwp[(size_t)i*H];
    float wk = kwp[(size_t)i*H];
    float wv = vwp[(size_t)i*H];
    float4 f0 = *(const float4*)&fsT[i][0];
    float4 f1 = *(const float4*)&fsT[i][4];
    float fv[8] = {f0.x,f0.y,f0.z,f0.w, f1.x,f1.y,f1.z,f1.w};
    #pragma unroll
    for (int r=0;r<TN3;r++){
      Qr[r] = fmaf(fv[r], wq, Qr[r]);
      Kr[r] = fmaf(fv[r], wk, Kr[r]);
      Vr[r] = fmaf(fv[r], wv, Vr[r]);
    }
  }
  #pragma unroll
  for (int r=0;r<TN3;r++){
    Qs[r][t] = Qr[r];
    KVs[r][t] = make_float2(Kr[r], Vr[r]);
  }
  __syncthreads();
  // attention: wave W handles nodes r = 2*p + W; each lane covers dims lane, lane+64
  const float invs = 0.08838834764831845f;  // 1/sqrt(128)
  #pragma unroll
  for (int p=0;p<4;p++){
    const int r = 2*p + W;
    const float qa = Qs[r][lane]   * invs;
    const float qb2 = Qs[r][lane+64] * invs;
    float sA=0.f, aA=0.f, sB=0.f, aB=0.f;
    const float4* kvp = (const float4*)&KVs[r][0];
    #pragma unroll 4
    for (int oo=0; oo<H/2; oo++){
      float4 kv2 = kvp[oo];                // two (K,V) pairs per b128
      float eA0 = __expf(qa*kv2.x);  sA += eA0; aA = fmaf(eA0, kv2.y, aA);
      float eA1 = __expf(qa*kv2.z);  sA += eA1; aA = fmaf(eA1, kv2.w, aA);
      float eB0 = __expf(qb2*kv2.x); sB += eB0; aB = fmaf(eB0, kv2.y, aB);
      float eB1 = __expf(qb2*kv2.z); sB += eB1; aB = fmaf(eB1, kv2.w, aB);
    }
    As2T[lane][r]    = aA/sA;
    As2T[lane+64][r] = aB/sB;
  }
  __syncthreads();
  // fc: g[r] = sum_i As2T[i][r] * fcw[i][t]  (fcw read ONCE per block)
  const float* fcwp = fcw + (size_t)v*H*H + t;
  const float fcbv = fcb[v*H+t];
  float g[TN3];
  #pragma unroll
  for (int r=0;r<TN3;r++) g[r] = fcbv;
  for (int i=0;i<H;i++){
    float fw = fcwp[(size_t)i*H];
    float4 a0 = *(const float4*)&As2T[i][0];
    float4 a1v = *(const float4*)&As2T[i][4];
    g[0] = fmaf(a0.x, fw, g[0]);  g[1] = fmaf(a0.y, fw, g[1]);
    g[2] = fmaf(a0.z, fw, g[2]);  g[3] = fmaf(a0.w, fw, g[3]);
    g[4] = fmaf(a1v.x, fw, g[4]); g[5] = fmaf(a1v.y, fw, g[5]);
    g[6] = fmaf(a1v.z, fw, g[6]); g[7] = fmaf(a1v.w, fw, g[7]);
  }
  const float cwv = confw[v*H+t];
  const float cbv = confb[v];
  #pragma unroll
  for (int r=0;r<TN3;r++){
    g[r] = fmaxf(g[r], 0.f);
    float psm = g[r]*cwv;
    #pragma unroll
    for (int o=32;o>0;o>>=1) psm += __shfl_down(psm,o);
    if (lane==0) rbuf2[r][W] = psm;
  }
  __syncthreads();
  #pragma unroll
  for (int r=0;r<TN3;r++){
    const float conf = rbuf2[r][0] + rbuf2[r][1] + cbv;
    feat2[((size_t)v*N + n0 + r)*H + t] = g[r]*conf;
  }
}

// ---------------- K4: final classifier [N, V*H] @ [V*H, C] ----------------
__global__ __launch_bounds__(64) void k4_cls(
    const float* __restrict__ feat2,
    const float* __restrict__ mm_w, const float* __restrict__ mm_b,
    float* __restrict__ out)
{
  const int n = blockIdx.x, t = threadIdx.x;
  float a[C] = {0,0,0,0,0};
  for (int j=t; j<V*H; j+=64){
    int vv = j >> 7, hh = j & (H-1);
    float f = feat2[((size_t)vv*N + n)*H + hh];
    #pragma unroll
    for (int c=0;c<C;c++) a[c] = fmaf(f, mm_w[j*C+c], a[c]);
  }
  #pragma unroll
  for (int c=0;c<C;c++){
    #pragma unroll
    for (int o=32;o>0;o>>=1) a[c] += __shfl_down(a[c],o);
  }
  if (t==0){
    #pragma unroll
    for (int c=0;c<C;c++) out[(size_t)n*C+c] = a[c] + mm_b[c];
  }
}

extern "C" void kernel_launch(void* const* d_in, const int* in_sizes, int n_in,
                              void* d_out, int out_size, void* d_ws, size_t ws_size,
                              hipStream_t stream)
{
  (void)in_sizes; (void)n_in; (void)out_size; (void)ws_size;
  const float* data  = (const float*)d_in[0];
  const int*   adj   = (const int*)d_in[1];
  const float* gac_w = (const float*)d_in[2];
  const float* gac_b = (const float*)d_in[3];
  const float* a1    = (const float*)d_in[4];
  const float* a2    = (const float*)d_in[5];
  const float* mlp_w = (const float*)d_in[6];
  const float* mlp_b = (const float*)d_in[7];
  const float* q_w   = (const float*)d_in[8];
  const float* q_b   = (const float*)d_in[9];
  const float* k_w   = (const float*)d_in[10];
  const float* k_b   = (const float*)d_in[11];
  const float* v_w   = (const float*)d_in[12];
  const float* v_b   = (const float*)d_in[13];
  const float* fc_w  = (const float*)d_in[14];
  const float* fc_b  = (const float*)d_in[15];
  const float* cw    = (const float*)d_in[16];
  const float* cb    = (const float*)d_in[17];
  const float* mm_w  = (const float*)d_in[18];
  const float* mm_b  = (const float*)d_in[19];

  float* ws = (float*)d_ws;
  const size_t VNH = (size_t)V*N*H;
  float* mlp   = ws;
  float* feat  = ws + VNH;
  float* feat2 = ws + 2*VNH;
  float* e1    = ws + 3*VNH;
  float* e2    = e1 + (size_t)V*N;
  unsigned short* hT = (unsigned short*)(e2 + (size_t)V*N);  // [V][H][N] bf16

  k1_gemm<<<dim3(N/TN1, V), 256, 0, stream>>>(data, gac_w, mlp_w, a1, a2,
                                              hT, mlp, e1, e2);
  k2_attn<<<dim3(N/16, V),  512, 0, stream>>>(hT, adj, e1, e2, mlp, gac_b, mlp_b, feat);
  k3_sgfe<<<dim3(N/TN3, V), 128, 0, stream>>>(feat, q_w, q_b, k_w, k_b, v_w, v_b,
                                              fc_w, fc_b, cw, cb, feat2);
  k4_cls<<<dim3(N),          64, 0, stream>>>(feat2, mm_w, mm_b, (float*)d_out);
}